// Round 10
// baseline (235.645 us; speedup 1.0000x reference)
//
#include <hip/hip_runtime.h>

// Problem constants: B=16, NH=8, DH=64, NG=4, NC=512, CG=128, GH=2, H=W=32,
// HW=1024, Hs=Ws=16, NS=256, scale=0.125, ORF*off_range = 2/15.
// External buffers fp32; internal tensors bf16.

typedef __attribute__((ext_vector_type(8))) short short8;
typedef __attribute__((ext_vector_type(4))) float f32x4;

__device__ __forceinline__ float bf2f(ushort u) {
    union { uint i; float f; } c; c.i = ((uint)u) << 16; return c.f;
}
__device__ __forceinline__ float bflou(uint u) {
    union { uint i; float f; } c; c.i = u << 16; return c.f;
}
__device__ __forceinline__ float bfhiu(uint u) {
    union { uint i; float f; } c; c.i = u & 0xffff0000u; return c.f;
}
__device__ __forceinline__ ushort f2bf(float f) {
    union { float f; uint i; } c; c.f = f;
    uint x = c.i;
    return (ushort)((x + 0x7fffu + ((x >> 16) & 1u)) >> 16);  // RNE
}
__device__ __forceinline__ float sat(float v, float lim) {
    return fminf(fmaxf(v, -lim), lim);  // NaN-flushing clamp
}
__device__ __forceinline__ f32x4 mfma_bf16(short8 a, short8 b, f32x4 c) {
    return __builtin_amdgcn_mfma_f32_16x16x32_bf16(a, b, c, 0, 0, 0);
}
// Direct global->LDS DMA, 16B per lane. LDS dest is wave-uniform base + lane*16.
__device__ __forceinline__ void gload16(const void* g, void* lds) {
    __builtin_amdgcn_global_load_lds((const __attribute__((address_space(1))) uint*)g,
                                     (__attribute__((address_space(3))) uint*)lds,
                                     16, 0, 0);
}

// ---------------------------------------------------------------------------
// One-time preps
__global__ __launch_bounds__(256) void prep_w(const float* __restrict__ w0,
                                              const float* __restrict__ w1,
                                              const float* __restrict__ w2,
                                              const float* __restrict__ w3,
                                              ushort* __restrict__ dst) {
    int widx = blockIdx.y;
    const float* src = widx == 0 ? w0 : widx == 1 ? w1 : widx == 2 ? w2 : w3;
    int i = blockIdx.x * 256 + threadIdx.x;
    float4 f = ((const float4*)src)[i];
    ushort4 u;
    u.x = f2bf(f.x); u.y = f2bf(f.y); u.z = f2bf(f.z); u.w = f2bf(f.w);
    ((ushort4*)(dst + (size_t)widx * 262144))[i] = u;
}

// rpe [8][63][63] fp32 -> padded bf16-PAIR table [8][5184] uint.
// tb2[h][i] = (bf16(T[i]), bf16(T[i+1])) where T is the zero-padded 72x72
// table (valid region rows/cols [4,66]). Any base gives an aligned 4B pair.
__global__ __launch_bounds__(256) void prep_rpe(const float* __restrict__ rpe,
                                                uint* __restrict__ tb2) {
    int h = blockIdx.x, t = threadIdx.x;
    for (int i = t; i < 5184; i += 256) {
        int yy = i / 72, xx = i - yy * 72;
        int sy = yy - 4, sx = xx - 4;
        float v0 = ((unsigned)sy < 63u && (unsigned)sx < 63u)
                       ? rpe[(size_t)h * 3969 + sy * 63 + sx] : 0.f;
        int j = i + 1;
        int y1 = j / 72, x1 = j - y1 * 72;
        int sy1 = y1 - 4, sx1 = x1 - 4;
        float v1 = (j < 5184 && (unsigned)sy1 < 63u && (unsigned)sx1 < 63u)
                       ? rpe[(size_t)h * 3969 + sy1 * 63 + sx1] : 0.f;
        tb2[(size_t)h * 5184 + i] = (uint)f2bf(v0) | ((uint)f2bf(v1) << 16);
    }
}

// x [b][512][1024] fp32 -> xbT [bl][1024][512] bf16 (transpose+convert)
__global__ __launch_bounds__(256) void prep_xT(const float* __restrict__ x,
                                               ushort* __restrict__ xbT, int b0) {
    __shared__ float tile[64][33];
    int n0 = blockIdx.x * 32, c0 = blockIdx.y * 64, bl = blockIdx.z, bg = b0 + bl;
    int t = threadIdx.x;
#pragma unroll
    for (int it = 0; it < 8; it++) {
        int cr = it * 8 + (t >> 5), col = t & 31;
        tile[cr][col] = x[((size_t)bg * 512 + c0 + cr) * 1024 + n0 + col];
    }
    __syncthreads();
#pragma unroll
    for (int it = 0; it < 8; it++) {
        int nr = it * 4 + (t >> 6), cc = t & 63;
        xbT[((size_t)bl * 1024 + n0 + nr) * 512 + c0 + cc] = f2bf(tile[cc][nr]);
    }
}

// ---------------------------------------------------------------------------
// Fused K+V GEMM: A = Wk||Wv (1024x512, contiguous in Wbf), B = xsT[b] (256x512).
// m-blocks 0..7 -> kT[b][s][c] (transposed ushort4 pack), 8..15 -> vS[b][c][s].
__global__ __launch_bounds__(256) void gemm_kv(const ushort* __restrict__ A,
                                               const ushort* __restrict__ Bm,
                                               const float* __restrict__ bk,
                                               const float* __restrict__ bv,
                                               ushort* __restrict__ kT,
                                               ushort* __restrict__ vS) {
    __shared__ __align__(16) ushort As[64 * 64];
    __shared__ __align__(16) ushort Bs[64 * 64];
    int b = blockIdx.z, m0 = blockIdx.y * 64, n0 = blockIdx.x * 64;
    const ushort* Bp = Bm + (size_t)b * (256 * 512);
    int t = threadIdx.x, lane = t & 63, col = lane & 15, quad = lane >> 4;
    int w = t >> 6;
    int m_off = (w & 1) * 32, n_off = (w >> 1) * 32;
    f32x4 acc[2][2] = {};
    for (int k0 = 0; k0 < 512; k0 += 64) {
        __syncthreads();
#pragma unroll
        for (int it = 0; it < 2; it++) {
            int i = it * 256 + t;            // 16B slot index, 512 per matrix
            int r = i >> 3, pslot = i & 7;
            int part = pslot ^ (r & 7);      // pre-swizzled global part
            int ub = (it * 256 + (t & ~63)) * 8;  // wave-uniform LDS ushort base
            gload16(&A[(size_t)(m0 + r) * 512 + k0 + part * 8], &As[ub]);
            gload16(&Bp[(size_t)(n0 + r) * 512 + k0 + part * 8], &Bs[ub]);
        }
        __syncthreads();
#pragma unroll
        for (int kk = 0; kk < 2; kk++) {
            int ra0 = m_off + col, ra1 = m_off + 16 + col;
            int rb0 = n_off + col, rb1 = n_off + 16 + col;
            short8 a0 = *(const short8*)&As[ra0 * 64 + (((kk * 4 + quad) ^ (ra0 & 7)) * 8)];
            short8 a1 = *(const short8*)&As[ra1 * 64 + (((kk * 4 + quad) ^ (ra1 & 7)) * 8)];
            short8 b0v = *(const short8*)&Bs[rb0 * 64 + (((kk * 4 + quad) ^ (rb0 & 7)) * 8)];
            short8 b1v = *(const short8*)&Bs[rb1 * 64 + (((kk * 4 + quad) ^ (rb1 & 7)) * 8)];
            acc[0][0] = mfma_bf16(a0, b0v, acc[0][0]);
            acc[0][1] = mfma_bf16(a0, b1v, acc[0][1]);
            acc[1][0] = mfma_bf16(a1, b0v, acc[1][0]);
            acc[1][1] = mfma_bf16(a1, b1v, acc[1][1]);
        }
    }
#pragma unroll
    for (int mi = 0; mi < 2; mi++)
#pragma unroll
        for (int ni = 0; ni < 2; ni++) {
            int mg = m0 + m_off + mi * 16 + quad * 4;
            int ng = n0 + n_off + ni * 16 + col;
            f32x4 vv = acc[mi][ni];
            if (m0 < 512) {  // K half: kT[b][ng][mg], packed across mg
                ushort4 pk;
                pk.x = f2bf(sat(vv[0] + bk[mg + 0], 1e4f));
                pk.y = f2bf(sat(vv[1] + bk[mg + 1], 1e4f));
                pk.z = f2bf(sat(vv[2] + bk[mg + 2], 1e4f));
                pk.w = f2bf(sat(vv[3] + bk[mg + 3], 1e4f));
                *(ushort4*)&kT[(size_t)b * 131072 + (size_t)ng * 512 + mg] = pk;
            } else {         // V half: vS[b][mg-512][ng]
                int mv = mg - 512;
#pragma unroll
                for (int r = 0; r < 4; r++) {
                    float v = sat(vv[r] + bv[mv + r], 1e4f);
                    vS[(size_t)b * 131072 + (size_t)(mv + r) * 256 + ng] = f2bf(v);
                }
            }
        }
}

// ---------------------------------------------------------------------------
// 128x128-tile GEMM (for qx / Wo). global_load_lds staging (m97 pattern),
// XOR-swizzled unpadded LDS via pre-swizzled global source addresses.
template <int OUT_T, int CINT>
__global__ __launch_bounds__(256, 4) void gemm128(const ushort* __restrict__ A,
                                                  const ushort* __restrict__ Bm,
                                                  const float* __restrict__ bias,
                                                  void* __restrict__ C, int K,
                                                  size_t sB, size_t sC, int ldc, size_t c0) {
    __shared__ __align__(16) ushort As[128 * 64];
    __shared__ __align__(16) ushort Bs[128 * 64];
    int b = blockIdx.z, m0 = blockIdx.y * 128, n0 = blockIdx.x * 128;
    const ushort* Bp = Bm + (size_t)b * sB;
    size_t cb = c0 + (size_t)b * sC;
    int t = threadIdx.x, w = t >> 6, lane = t & 63, col = lane & 15, quad = lane >> 4;
    int m_off = (w & 1) * 64, n_off = (w >> 1) * 64;
    f32x4 acc[4][4] = {};
    for (int k0 = 0; k0 < K; k0 += 64) {
        __syncthreads();
#pragma unroll
        for (int it = 0; it < 4; it++) {
            int i = it * 256 + t;            // 16B slot index, 1024 per matrix
            int r = i >> 3, pslot = i & 7;
            int part = pslot ^ (r & 7);      // pre-swizzled global part
            int ub = (it * 256 + (t & ~63)) * 8;  // wave-uniform LDS ushort base
            gload16(&A[(size_t)(m0 + r) * K + k0 + part * 8], &As[ub]);
            gload16(&Bp[(size_t)(n0 + r) * K + k0 + part * 8], &Bs[ub]);
        }
        __syncthreads();
#pragma unroll
        for (int kk = 0; kk < 2; kk++) {
            short8 af[4], bf[4];
#pragma unroll
            for (int mi = 0; mi < 4; mi++) {
                int ra = m_off + mi * 16 + col;
                af[mi] = *(const short8*)&As[ra * 64 + (((kk * 4 + quad) ^ (ra & 7)) * 8)];
            }
#pragma unroll
            for (int ni = 0; ni < 4; ni++) {
                int rb = n_off + ni * 16 + col;
                bf[ni] = *(const short8*)&Bs[rb * 64 + (((kk * 4 + quad) ^ (rb & 7)) * 8)];
            }
#pragma unroll
            for (int mi = 0; mi < 4; mi++)
#pragma unroll
                for (int ni = 0; ni < 4; ni++)
                    acc[mi][ni] = mfma_bf16(af[mi], bf[ni], acc[mi][ni]);
        }
    }
#pragma unroll
    for (int mi = 0; mi < 4; mi++)
#pragma unroll
        for (int ni = 0; ni < 4; ni++) {
            int mg = m0 + m_off + mi * 16 + quad * 4;
            int ng = n0 + n_off + ni * 16 + col;
            f32x4 vv = acc[mi][ni];
            if (OUT_T == 1) {
                ushort4 pk;
                pk.x = f2bf(sat(vv[0] + bias[mg + 0], 1e4f));
                pk.y = f2bf(sat(vv[1] + bias[mg + 1], 1e4f));
                pk.z = f2bf(sat(vv[2] + bias[mg + 2], 1e4f));
                pk.w = f2bf(sat(vv[3] + bias[mg + 3], 1e4f));
                *(ushort4*)&((ushort*)C)[cb + (size_t)ng * ldc + mg] = pk;
            } else {
#pragma unroll
                for (int r = 0; r < 4; r++) {
                    float v = sat(vv[r] + bias[mg + r], 1e4f);
                    if (CINT) ((ushort*)C)[cb + (size_t)(mg + r) * ldc + ng] = f2bf(v);
                    else ((float*)C)[cb + (size_t)(mg + r) * ldc + ng] = v;
                }
            }
        }
}

// ---------------------------------------------------------------------------
// Offset network + FUSED bilinear sampling (sample_x merged in, R9-verified).
__global__ __launch_bounds__(64) void offset_net(
    const ushort* __restrict__ qT, const float* __restrict__ dww,
    const float* __restrict__ dwb, const float* __restrict__ lng,
    const float* __restrict__ lnb, const float* __restrict__ pww,
    const ushort* __restrict__ xbT, float* __restrict__ pos,
    ushort* __restrict__ xsT, float* __restrict__ out, int b0) {
    int n = blockIdx.y, sp = blockIdx.x, bl = n >> 2, bg = b0 + bl, g = n & 3;
    int i = sp >> 4, j = sp & 15, lane = threadIdx.x;
    int c0 = lane, c1 = lane + 64;
    float a0 = dwb[c0], a1 = dwb[c1];
#pragma unroll
    for (int dy = 0; dy < 3; dy++) {
        int yy = 2 * i - 1 + dy;
        if (yy < 0 || yy > 31) continue;
#pragma unroll
        for (int dx = 0; dx < 3; dx++) {
            int xx = 2 * j - 1 + dx;
            if (xx < 0 || xx > 31) continue;
            const ushort* qrow = qT + ((size_t)bl * 1024 + yy * 32 + xx) * 512 + g * 128;
            a0 += dww[c0 * 9 + dy * 3 + dx] * bf2f(qrow[c0]);
            a1 += dww[c1 * 9 + dy * 3 + dx] * bf2f(qrow[c1]);
        }
    }
    float s = a0 + a1, s2 = a0 * a0 + a1 * a1;
#pragma unroll
    for (int off = 1; off < 64; off <<= 1) {
        s += __shfl_xor(s, off);
        s2 += __shfl_xor(s2, off);
    }
    float mu = s * (1.f / 128.f);
    float var = s2 * (1.f / 128.f) - mu * mu;
    float rstd = rsqrtf(fmaxf(var, 0.f) + 1e-5f);
    float g0 = (a0 - mu) * rstd * lng[c0] + lnb[c0];
    float g1 = (a1 - mu) * rstd * lng[c1] + lnb[c1];
    g0 = 0.5f * g0 * (1.f + erff(g0 * 0.70710678118654752f));
    g1 = 0.5f * g1 * (1.f + erff(g1 * 0.70710678118654752f));
    float p0 = g0 * pww[c0] + g1 * pww[c1];
    float p1 = g0 * pww[128 + c0] + g1 * pww[128 + c1];
#pragma unroll
    for (int off = 1; off < 64; off <<= 1) {
        p0 += __shfl_xor(p0, off);
        p1 += __shfl_xor(p1, off);
    }
    // pos on all lanes (identical arithmetic to the old lane-0 path)
    float offy = tanhf(p0) * (2.f / 15.f);
    float offx = tanhf(p1) * (2.f / 15.f);
    float ry = ((float)i + 0.5f) * (2.f / 15.f) - 1.f;
    float rx = ((float)j + 0.5f) * (2.f / 15.f) - 1.f;
    float py = sat(offy + ry, 1.2f), px = sat(offx + rx, 1.2f);
    if (lane == 0) {
        size_t ol = ((size_t)(bl * 4 + g) * 256 + sp) * 2;   // chunk-local
        pos[ol] = py; pos[ol + 1] = px;
        size_t og = ((size_t)(bg * 4 + g) * 256 + sp) * 2;   // global out offset
        out[8388608 + og] = py;  out[8388608 + og + 1] = px;
        out[8421376 + og] = ry;  out[8421376 + og + 1] = rx;
    }
    // fused bilinear sample: channels c0, c1 (same math as old sample_x)
    float gx = (px + 1.f) * 15.5f;
    float gy = (py + 1.f) * 15.5f;
    float x0f = floorf(gx), y0f = floorf(gy);
    int ix0 = (int)x0f, iy0 = (int)y0f;
    float wx1 = gx - x0f, wx0 = 1.f - wx1, wy1 = gy - y0f, wy0 = 1.f - wy1;
    const ushort* xb = xbT + (size_t)bl * 1024 * 512 + g * 128;
    float s0 = 0.f, s1 = 0.f;
#define CORNER(ix, iy, wgt)                                                  \
    if ((unsigned)(ix) < 32u && (unsigned)(iy) < 32u) {                      \
        size_t o = (size_t)((iy) * 32 + (ix)) * 512;                         \
        s0 += (wgt) * bf2f(xb[o + c0]);                                      \
        s1 += (wgt) * bf2f(xb[o + c1]);                                      \
    }
    CORNER(ix0, iy0, wx0 * wy0)
    CORNER(ix0 + 1, iy0, wx1 * wy0)
    CORNER(ix0, iy0 + 1, wx0 * wy1)
    CORNER(ix0 + 1, iy0 + 1, wx1 * wy1)
#undef CORNER
    size_t xo = ((size_t)bl * 256 + sp) * 512 + g * 128;
    xsT[xo + c0] = f2bf(sat(s0, 64.f));
    xsT[xo + c1] = f2bf(sat(s1, 64.f));
}

// ---------------------------------------------------------------------------
// Fused attention v14: two-half s-split (flash-style, NO rescale needed since
// no-max softmax makes exp values half-independent).
//  - Halves the AGPR requirement: acc[8] (32) + acc2[4] (16) = 48 AGPR peak,
//    vs 64+16 = 80 before -> ~32 arch regs of slack at (256,4) -> the 13-reg
//    spill (27 MB excess WRITE in R9) should vanish while KEEPING 4 blocks/CU.
//  - Identical arithmetic: P = exp(clamped logits), acc2 and the scalar sums
//    accumulate across halves, single normalize at the end.
//  - LDS: A=[0,16KB) K-half (128x64 swz) / Ts overlay; B=[16KB,32KB) P-half
//    (64x128 swz, wave-private rows); + sW4/sBase = 37,888 B -> 4 blocks/CU.
//  - Ts slice loaded twice (once per half, L2-resident, ~free). 7 barriers.
__global__ __launch_bounds__(256, 4) void fused_attn(const ushort* __restrict__ qT,
                                                     const ushort* __restrict__ kT,
                                                     const ushort* __restrict__ vS,
                                                     const uint* __restrict__ tb2,
                                                     const float* __restrict__ pos,
                                                     ushort* __restrict__ outT) {
    __shared__ __align__(16) ushort KP[256 * 64];  // A: K-half/Ts; B: P-half
    __shared__ float4 sW4[256];
    __shared__ int sBase[256];
    int bh = blockIdx.y, bl = bh >> 3, h = bh & 7, g = h >> 1;
    int m0 = blockIdx.x * 64;
    int t = threadIdx.x;
    int w = t >> 6, lane = t & 63, col = lane & 15, quad = lane >> 4;
    int mw = w * 16;
    // Q fragment: issue early, latency hides under staging.
    const ushort* qrow = qT + ((size_t)bl * 1024 + m0 + mw + col) * 512 + h * 64;
    short8 a0 = *(const short8*)&qrow[quad * 8];
    short8 a1 = *(const short8*)&qrow[32 + quad * 8];
    const ushort* kb = kT + (size_t)bl * 256 * 512 + h * 64;
    // stage K half 0 (rows 0..127) into A
    for (int i = t; i < 1024; i += 256) {
        int sl = i >> 3, part = i & 7;
        *(uint4*)&KP[sl * 64 + ((part ^ (sl & 7)) * 8)] =
            *(const uint4*)&kb[(size_t)sl * 512 + part * 8];
    }
    {
        int s = t;
        float psy = pos[(size_t)(bl * 4 + g) * 512 + 2 * s];
        float psx = pos[(size_t)(bl * 4 + g) * 512 + 2 * s + 1];
        float syf = 15.5f - 15.5f * psy;
        float sxf = 15.5f - 15.5f * psx;
        float fy = floorf(syf), fx = floorf(sxf);
        float wy1 = syf - fy, wy0 = 1.f - wy1;
        float wx1 = sxf - fx, wx0 = 1.f - wx1;
        sBase[s] = ((int)fy + 4) * 72 + (int)fx + 4;   // slice-local (row rel. m0>>5)
        sW4[s] = make_float4(wx0 * wy0, wx1 * wy0, wx0 * wy1, wx1 * wy1);
    }
    __syncthreads();  // b0
    const uint4* tsrc = (const uint4*)(tb2 + (size_t)h * 5184 + (m0 >> 5) * 72);
    const uint* Tsl = (const uint*)KP;
    int cw = (mw >> 5) * 72 + (mw & 31) + quad * 4;
    const ushort* vp = vS + ((size_t)bl * 512 + h * 64) * 256;
    int lrA = mw + col, xA = lrA & 7;
    f32x4 acc2[4] = {};
    float sr_[4] = {0.f, 0.f, 0.f, 0.f};
#pragma unroll
    for (int hh = 0; hh < 2; hh++) {
        f32x4 acc[8] = {};
        // QK half: 8 frags over K rows hh*128 .. hh*128+127 (staged in A)
#pragma unroll
        for (int fi = 0; fi < 8; fi++) {
            int sl = fi * 16 + col;
            int x = sl & 7;
            short8 b0v = *(const short8*)&KP[sl * 64 + ((quad ^ x) * 8)];
            short8 b1v = *(const short8*)&KP[sl * 64 + (((quad + 4) ^ x) * 8)];
            acc[fi] = mfma_bf16(a0, b0v, acc[fi]);
            acc[fi] = mfma_bf16(a1, b1v, acc[fi]);
        }
        __syncthreads();  // b1/b5: K-half dead (Ts needs bytes [0,11808) = A rows 0..92)
        {
            uint4 ts0 = tsrc[t];
            uint4 ts1 = tsrc[t + 256];
            uint4 ts2 = (t + 512 < 738) ? tsrc[t + 512] : make_uint4(0, 0, 0, 0);
            uint4* Tsl4 = (uint4*)KP;
            Tsl4[t] = ts0;
            Tsl4[t + 256] = ts1;
            if (t + 512 < 738) Tsl4[t + 512] = ts2;
        }
        __syncthreads();  // b2/b6
        // bias taps + exp + partial sums
#pragma unroll
        for (int fi = 0; fi < 8; fi++) {
            int s = hh * 128 + fi * 16 + col;
            int base = sBase[s] + cw;
            float4 w4 = sW4[s];
            uint p00 = Tsl[base], p01 = Tsl[base + 2], p02 = Tsl[base + 4];
            uint p10 = Tsl[base + 72], p11 = Tsl[base + 74], p12 = Tsl[base + 76];
            float t0[5], t1[5];
            t0[0] = bflou(p00); t0[1] = bfhiu(p00); t0[2] = bflou(p01);
            t0[3] = bfhiu(p01); t0[4] = bflou(p02);
            t1[0] = bflou(p10); t1[1] = bfhiu(p10); t1[2] = bflou(p11);
            t1[3] = bfhiu(p11); t1[4] = bflou(p12);
#pragma unroll
            for (int r = 0; r < 4; r++) {
                float bias = w4.x * t0[r] + w4.y * t0[r + 1] + w4.z * t1[r] + w4.w * t1[r + 1];
                float e = __expf(sat(acc[fi][r] * 0.125f + bias, 64.f));
                acc[fi][r] = e;
                sr_[r] += e;
            }
        }
        if (hh == 0) {
            __syncthreads();  // b3: all waves done reading Ts before K2 overwrites A
            // stage K half 1 (rows 128..255) into A
            for (int i = t; i < 1024; i += 256) {
                int sl = i >> 3, part = i & 7;
                *(uint4*)&KP[sl * 64 + ((part ^ (sl & 7)) * 8)] =
                    *(const uint4*)&kb[(size_t)(128 + sl) * 512 + part * 8];
            }
        }
        // P-half -> B (wave-private rows [mw,mw+16), row stride 128, swizzled)
#pragma unroll
        for (int fi = 0; fi < 8; fi++)
#pragma unroll
            for (int r = 0; r < 4; r++) {
                int lr = mw + quad * 4 + r;
                int sc = fi * 16 + col;
                KP[8192 + lr * 128 + (((sc >> 3) ^ (lr & 7)) * 8) + (sc & 7)] =
                    f2bf(acc[fi][r]);
            }
        // PV half: acc2 += P_half x V_half (wave-local P reads; V from global/L2)
#pragma unroll
        for (int ks = 0; ks < 4; ks++) {
            short8 a = *(const short8*)&KP[8192 + lrA * 128 + (((ks * 4 + quad) ^ xA) * 8)];
#pragma unroll
            for (int ni = 0; ni < 4; ni++) {
                short8 bb = *(const short8*)&vp[(size_t)(ni * 16 + col) * 256 +
                                                hh * 128 + ks * 32 + quad * 8];
                acc2[ni] = mfma_bf16(a, bb, acc2[ni]);
            }
        }
        if (hh == 0) __syncthreads();  // b4: K2 staged before QK2 reads A
    }
    // final normalize: sums accumulated across both halves
    float rinv_[4];
#pragma unroll
    for (int r = 0; r < 4; r++) {
        float sr = sr_[r];
#pragma unroll
        for (int off = 1; off < 16; off <<= 1) sr += __shfl_xor(sr, off);
        rinv_[r] = 1.f / sr;
    }
#pragma unroll
    for (int ni = 0; ni < 4; ni++)
#pragma unroll
        for (int r = 0; r < 4; r++) {
            int ml = mw + quad * 4 + r;
            float val = sat(acc2[ni][r] * rinv_[r], 64.f);
            outT[((size_t)bl * 1024 + m0 + ml) * 512 + h * 64 + ni * 16 + col] = f2bf(val);
        }
}

// ---------------------------------------------------------------------------
extern "C" void kernel_launch(void* const* d_in, const int* in_sizes, int n_in,
                              void* d_out, int out_size, void* d_ws, size_t ws_size,
                              hipStream_t stream) {
    const float* x   = (const float*)d_in[0];
    const float* Wq  = (const float*)d_in[1];
    const float* bq  = (const float*)d_in[2];
    const float* Wk  = (const float*)d_in[3];
    const float* bk  = (const float*)d_in[4];
    const float* Wv  = (const float*)d_in[5];
    const float* bv  = (const float*)d_in[6];
    const float* Wo  = (const float*)d_in[7];
    const float* bo  = (const float*)d_in[8];
    const float* dww = (const float*)d_in[9];
    const float* dwb = (const float*)d_in[10];
    const float* lng = (const float*)d_in[11];
    const float* lnb = (const float*)d_in[12];
    const float* pww = (const float*)d_in[13];
    const float* rpe = (const float*)d_in[14];
    float* out = (float*)d_out;

    char* wsb = (char*)d_ws;
    size_t off = 256;
    const size_t Wbf_bytes = (size_t)4 * 262144 * 2;  // 2 MB
    const size_t tb2_bytes = (size_t)8 * 5184 * 4;    // ~162 KB (pair-packed)
    ushort* Wbf = (ushort*)(wsb + off); off += Wbf_bytes;
    uint*   tb2 = (uint*)(wsb + off);   off += tb2_bytes;
    size_t base = (off + 255) & ~(size_t)255;

    const size_t xbT_b = (size_t)1024 * 512 * 2;   // 1 MB
    const size_t qT_b  = (size_t)1024 * 512 * 2;   // 1 MB
    const size_t xsT_b = (size_t)256 * 512 * 2;    // 256 KB
    const size_t kT_b  = (size_t)256 * 512 * 2;    // 256 KB
    const size_t vS_b  = (size_t)512 * 256 * 2;    // 256 KB
    const size_t oT_b  = (size_t)1024 * 512 * 2;   // 1 MB
    const size_t pos_b = (size_t)4 * 256 * 2 * 4;  // 8 KB
    const size_t per_b = xbT_b + qT_b + xsT_b + kT_b + vS_b + oT_b + pos_b + 1024;
    long long avail = (long long)ws_size - (long long)base;
    int bc_cap = (int)(avail > 0 ? avail / (long long)per_b : 0);
    if (bc_cap < 1) bc_cap = 1;
    if (bc_cap > 16) bc_cap = 16;

    prep_w<<<dim3(256, 4), 256, 0, stream>>>(Wq, Wk, Wv, Wo, Wbf);
    prep_rpe<<<8, 256, 0, stream>>>(rpe, tb2);
    const ushort* Wqb = Wbf;
    const ushort* Wkb = Wbf + 262144;
    const ushort* Wob = Wbf + 3 * 262144;

    for (int b0 = 0; b0 < 16; b0 += bc_cap) {
        int bc = 16 - b0 < bc_cap ? 16 - b0 : bc_cap;
        char* p = wsb + base;
        ushort* xbT  = (ushort*)p; p += xbT_b * bc;
        ushort* qT   = (ushort*)p; p += qT_b * bc;
        ushort* xsT  = (ushort*)p; p += xsT_b * bc;
        ushort* kT   = (ushort*)p; p += kT_b * bc;
        ushort* vS   = (ushort*)p; p += vS_b * bc;
        ushort* outT = (ushort*)p; p += oT_b * bc;
        float*  pos  = (float*)p;

        prep_xT<<<dim3(32, 8, bc), 256, 0, stream>>>(x, xbT, b0);
        gemm128<1, 1><<<dim3(8, 4, bc), 256, 0, stream>>>(Wqb, xbT, bq, qT, 512,
                                                          (size_t)1024 * 512, (size_t)1024 * 512, 512, 0);
        offset_net<<<dim3(256, 4 * bc), 64, 0, stream>>>(qT, dww, dwb, lng, lnb, pww,
                                                         xbT, pos, xsT, out, b0);
        gemm_kv<<<dim3(4, 16, bc), 256, 0, stream>>>(Wkb, xsT, bk, bv, kT, vS);
        fused_attn<<<dim3(16, 8 * bc), 256, 0, stream>>>(qT, kT, vS, tb2, pos, outT);
        gemm128<0, 0><<<dim3(8, 4, bc), 256, 0, stream>>>(Wob, outT, bo, d_out, 512,
                                                          (size_t)1024 * 512, (size_t)512 * 1024, 1024,
                                                          (size_t)b0 * 512 * 1024);
    }
}

// Round 11
// 228.476 us; speedup vs baseline: 1.0314x; 1.0314x over previous
//
#include <hip/hip_runtime.h>

// Problem constants: B=16, NH=8, DH=64, NG=4, NC=512, CG=128, GH=2, H=W=32,
// HW=1024, Hs=Ws=16, NS=256, scale=0.125, ORF*off_range = 2/15.
// External buffers fp32; internal tensors bf16.

typedef __attribute__((ext_vector_type(8))) short short8;
typedef __attribute__((ext_vector_type(4))) float f32x4;

__device__ __forceinline__ float bf2f(ushort u) {
    union { uint i; float f; } c; c.i = ((uint)u) << 16; return c.f;
}
__device__ __forceinline__ float bflou(uint u) {
    union { uint i; float f; } c; c.i = u << 16; return c.f;
}
__device__ __forceinline__ float bfhiu(uint u) {
    union { uint i; float f; } c; c.i = u & 0xffff0000u; return c.f;
}
__device__ __forceinline__ ushort f2bf(float f) {
    union { float f; uint i; } c; c.f = f;
    uint x = c.i;
    return (ushort)((x + 0x7fffu + ((x >> 16) & 1u)) >> 16);  // RNE
}
__device__ __forceinline__ float sat(float v, float lim) {
    return fminf(fmaxf(v, -lim), lim);  // NaN-flushing clamp
}
__device__ __forceinline__ f32x4 mfma_bf16(short8 a, short8 b, f32x4 c) {
    return __builtin_amdgcn_mfma_f32_16x16x32_bf16(a, b, c, 0, 0, 0);
}
// Direct global->LDS DMA, 16B per lane. LDS dest is wave-uniform base + lane*16.
__device__ __forceinline__ void gload16(const void* g, void* lds) {
    __builtin_amdgcn_global_load_lds((const __attribute__((address_space(1))) uint*)g,
                                     (__attribute__((address_space(3))) uint*)lds,
                                     16, 0, 0);
}

// ---------------------------------------------------------------------------
// One-time preps
__global__ __launch_bounds__(256) void prep_w(const float* __restrict__ w0,
                                              const float* __restrict__ w1,
                                              const float* __restrict__ w2,
                                              const float* __restrict__ w3,
                                              ushort* __restrict__ dst) {
    int widx = blockIdx.y;
    const float* src = widx == 0 ? w0 : widx == 1 ? w1 : widx == 2 ? w2 : w3;
    int i = blockIdx.x * 256 + threadIdx.x;
    float4 f = ((const float4*)src)[i];
    ushort4 u;
    u.x = f2bf(f.x); u.y = f2bf(f.y); u.z = f2bf(f.z); u.w = f2bf(f.w);
    ((ushort4*)(dst + (size_t)widx * 262144))[i] = u;
}

// rpe [8][63][63] fp32 -> padded bf16-PAIR table [8][5184] uint.
// tb2[h][i] = (bf16(T[i]), bf16(T[i+1])) where T is the zero-padded 72x72
// table (valid region rows/cols [4,66]). Any base gives an aligned 4B pair.
__global__ __launch_bounds__(256) void prep_rpe(const float* __restrict__ rpe,
                                                uint* __restrict__ tb2) {
    int h = blockIdx.x, t = threadIdx.x;
    for (int i = t; i < 5184; i += 256) {
        int yy = i / 72, xx = i - yy * 72;
        int sy = yy - 4, sx = xx - 4;
        float v0 = ((unsigned)sy < 63u && (unsigned)sx < 63u)
                       ? rpe[(size_t)h * 3969 + sy * 63 + sx] : 0.f;
        int j = i + 1;
        int y1 = j / 72, x1 = j - y1 * 72;
        int sy1 = y1 - 4, sx1 = x1 - 4;
        float v1 = (j < 5184 && (unsigned)sy1 < 63u && (unsigned)sx1 < 63u)
                       ? rpe[(size_t)h * 3969 + sy1 * 63 + sx1] : 0.f;
        tb2[(size_t)h * 5184 + i] = (uint)f2bf(v0) | ((uint)f2bf(v1) << 16);
    }
}

// x [b][512][1024] fp32 -> xbT [bl][1024][512] bf16 (transpose+convert)
__global__ __launch_bounds__(256) void prep_xT(const float* __restrict__ x,
                                               ushort* __restrict__ xbT, int b0) {
    __shared__ float tile[64][33];
    int n0 = blockIdx.x * 32, c0 = blockIdx.y * 64, bl = blockIdx.z, bg = b0 + bl;
    int t = threadIdx.x;
#pragma unroll
    for (int it = 0; it < 8; it++) {
        int cr = it * 8 + (t >> 5), col = t & 31;
        tile[cr][col] = x[((size_t)bg * 512 + c0 + cr) * 1024 + n0 + col];
    }
    __syncthreads();
#pragma unroll
    for (int it = 0; it < 8; it++) {
        int nr = it * 4 + (t >> 6), cc = t & 63;
        xbT[((size_t)bl * 1024 + n0 + nr) * 512 + c0 + cc] = f2bf(tile[cc][nr]);
    }
}

// ---------------------------------------------------------------------------
// Fused K+V GEMM: A = Wk||Wv (1024x512, contiguous in Wbf), B = xsT[b] (256x512).
// m-blocks 0..7 -> kT[b][s][c] (transposed ushort4 pack), 8..15 -> vS[b][c][s].
__global__ __launch_bounds__(256) void gemm_kv(const ushort* __restrict__ A,
                                               const ushort* __restrict__ Bm,
                                               const float* __restrict__ bk,
                                               const float* __restrict__ bv,
                                               ushort* __restrict__ kT,
                                               ushort* __restrict__ vS) {
    __shared__ __align__(16) ushort As[64 * 64];
    __shared__ __align__(16) ushort Bs[64 * 64];
    int b = blockIdx.z, m0 = blockIdx.y * 64, n0 = blockIdx.x * 64;
    const ushort* Bp = Bm + (size_t)b * (256 * 512);
    int t = threadIdx.x, lane = t & 63, col = lane & 15, quad = lane >> 4;
    int w = t >> 6;
    int m_off = (w & 1) * 32, n_off = (w >> 1) * 32;
    f32x4 acc[2][2] = {};
    for (int k0 = 0; k0 < 512; k0 += 64) {
        __syncthreads();
#pragma unroll
        for (int it = 0; it < 2; it++) {
            int i = it * 256 + t;            // 16B slot index, 512 per matrix
            int r = i >> 3, pslot = i & 7;
            int part = pslot ^ (r & 7);      // pre-swizzled global part
            int ub = (it * 256 + (t & ~63)) * 8;  // wave-uniform LDS ushort base
            gload16(&A[(size_t)(m0 + r) * 512 + k0 + part * 8], &As[ub]);
            gload16(&Bp[(size_t)(n0 + r) * 512 + k0 + part * 8], &Bs[ub]);
        }
        __syncthreads();
#pragma unroll
        for (int kk = 0; kk < 2; kk++) {
            int ra0 = m_off + col, ra1 = m_off + 16 + col;
            int rb0 = n_off + col, rb1 = n_off + 16 + col;
            short8 a0 = *(const short8*)&As[ra0 * 64 + (((kk * 4 + quad) ^ (ra0 & 7)) * 8)];
            short8 a1 = *(const short8*)&As[ra1 * 64 + (((kk * 4 + quad) ^ (ra1 & 7)) * 8)];
            short8 b0v = *(const short8*)&Bs[rb0 * 64 + (((kk * 4 + quad) ^ (rb0 & 7)) * 8)];
            short8 b1v = *(const short8*)&Bs[rb1 * 64 + (((kk * 4 + quad) ^ (rb1 & 7)) * 8)];
            acc[0][0] = mfma_bf16(a0, b0v, acc[0][0]);
            acc[0][1] = mfma_bf16(a0, b1v, acc[0][1]);
            acc[1][0] = mfma_bf16(a1, b0v, acc[1][0]);
            acc[1][1] = mfma_bf16(a1, b1v, acc[1][1]);
        }
    }
#pragma unroll
    for (int mi = 0; mi < 2; mi++)
#pragma unroll
        for (int ni = 0; ni < 2; ni++) {
            int mg = m0 + m_off + mi * 16 + quad * 4;
            int ng = n0 + n_off + ni * 16 + col;
            f32x4 vv = acc[mi][ni];
            if (m0 < 512) {  // K half: kT[b][ng][mg], packed across mg
                ushort4 pk;
                pk.x = f2bf(sat(vv[0] + bk[mg + 0], 1e4f));
                pk.y = f2bf(sat(vv[1] + bk[mg + 1], 1e4f));
                pk.z = f2bf(sat(vv[2] + bk[mg + 2], 1e4f));
                pk.w = f2bf(sat(vv[3] + bk[mg + 3], 1e4f));
                *(ushort4*)&kT[(size_t)b * 131072 + (size_t)ng * 512 + mg] = pk;
            } else {         // V half: vS[b][mg-512][ng]
                int mv = mg - 512;
#pragma unroll
                for (int r = 0; r < 4; r++) {
                    float v = sat(vv[r] + bv[mv + r], 1e4f);
                    vS[(size_t)b * 131072 + (size_t)(mv + r) * 256 + ng] = f2bf(v);
                }
            }
        }
}

// ---------------------------------------------------------------------------
// 128x128-tile GEMM (for qx / Wo). global_load_lds staging (m97 pattern),
// XOR-swizzled unpadded LDS via pre-swizzled global source addresses.
template <int OUT_T, int CINT>
__global__ __launch_bounds__(256, 4) void gemm128(const ushort* __restrict__ A,
                                                  const ushort* __restrict__ Bm,
                                                  const float* __restrict__ bias,
                                                  void* __restrict__ C, int K,
                                                  size_t sB, size_t sC, int ldc, size_t c0) {
    __shared__ __align__(16) ushort As[128 * 64];
    __shared__ __align__(16) ushort Bs[128 * 64];
    int b = blockIdx.z, m0 = blockIdx.y * 128, n0 = blockIdx.x * 128;
    const ushort* Bp = Bm + (size_t)b * sB;
    size_t cb = c0 + (size_t)b * sC;
    int t = threadIdx.x, w = t >> 6, lane = t & 63, col = lane & 15, quad = lane >> 4;
    int m_off = (w & 1) * 64, n_off = (w >> 1) * 64;
    f32x4 acc[4][4] = {};
    for (int k0 = 0; k0 < K; k0 += 64) {
        __syncthreads();
#pragma unroll
        for (int it = 0; it < 4; it++) {
            int i = it * 256 + t;            // 16B slot index, 1024 per matrix
            int r = i >> 3, pslot = i & 7;
            int part = pslot ^ (r & 7);      // pre-swizzled global part
            int ub = (it * 256 + (t & ~63)) * 8;  // wave-uniform LDS ushort base
            gload16(&A[(size_t)(m0 + r) * K + k0 + part * 8], &As[ub]);
            gload16(&Bp[(size_t)(n0 + r) * K + k0 + part * 8], &Bs[ub]);
        }
        __syncthreads();
#pragma unroll
        for (int kk = 0; kk < 2; kk++) {
            short8 af[4], bf[4];
#pragma unroll
            for (int mi = 0; mi < 4; mi++) {
                int ra = m_off + mi * 16 + col;
                af[mi] = *(const short8*)&As[ra * 64 + (((kk * 4 + quad) ^ (ra & 7)) * 8)];
            }
#pragma unroll
            for (int ni = 0; ni < 4; ni++) {
                int rb = n_off + ni * 16 + col;
                bf[ni] = *(const short8*)&Bs[rb * 64 + (((kk * 4 + quad) ^ (rb & 7)) * 8)];
            }
#pragma unroll
            for (int mi = 0; mi < 4; mi++)
#pragma unroll
                for (int ni = 0; ni < 4; ni++)
                    acc[mi][ni] = mfma_bf16(af[mi], bf[ni], acc[mi][ni]);
        }
    }
#pragma unroll
    for (int mi = 0; mi < 4; mi++)
#pragma unroll
        for (int ni = 0; ni < 4; ni++) {
            int mg = m0 + m_off + mi * 16 + quad * 4;
            int ng = n0 + n_off + ni * 16 + col;
            f32x4 vv = acc[mi][ni];
            if (OUT_T == 1) {
                ushort4 pk;
                pk.x = f2bf(sat(vv[0] + bias[mg + 0], 1e4f));
                pk.y = f2bf(sat(vv[1] + bias[mg + 1], 1e4f));
                pk.z = f2bf(sat(vv[2] + bias[mg + 2], 1e4f));
                pk.w = f2bf(sat(vv[3] + bias[mg + 3], 1e4f));
                *(ushort4*)&((ushort*)C)[cb + (size_t)ng * ldc + mg] = pk;
            } else {
#pragma unroll
                for (int r = 0; r < 4; r++) {
                    float v = sat(vv[r] + bias[mg + r], 1e4f);
                    if (CINT) ((ushort*)C)[cb + (size_t)(mg + r) * ldc + ng] = f2bf(v);
                    else ((float*)C)[cb + (size_t)(mg + r) * ldc + ng] = v;
                }
            }
        }
}

// ---------------------------------------------------------------------------
// Offset network + FUSED bilinear sampling (sample_x merged in, R9-verified).
__global__ __launch_bounds__(64) void offset_net(
    const ushort* __restrict__ qT, const float* __restrict__ dww,
    const float* __restrict__ dwb, const float* __restrict__ lng,
    const float* __restrict__ lnb, const float* __restrict__ pww,
    const ushort* __restrict__ xbT, float* __restrict__ pos,
    ushort* __restrict__ xsT, float* __restrict__ out, int b0) {
    int n = blockIdx.y, sp = blockIdx.x, bl = n >> 2, bg = b0 + bl, g = n & 3;
    int i = sp >> 4, j = sp & 15, lane = threadIdx.x;
    int c0 = lane, c1 = lane + 64;
    float a0 = dwb[c0], a1 = dwb[c1];
#pragma unroll
    for (int dy = 0; dy < 3; dy++) {
        int yy = 2 * i - 1 + dy;
        if (yy < 0 || yy > 31) continue;
#pragma unroll
        for (int dx = 0; dx < 3; dx++) {
            int xx = 2 * j - 1 + dx;
            if (xx < 0 || xx > 31) continue;
            const ushort* qrow = qT + ((size_t)bl * 1024 + yy * 32 + xx) * 512 + g * 128;
            a0 += dww[c0 * 9 + dy * 3 + dx] * bf2f(qrow[c0]);
            a1 += dww[c1 * 9 + dy * 3 + dx] * bf2f(qrow[c1]);
        }
    }
    float s = a0 + a1, s2 = a0 * a0 + a1 * a1;
#pragma unroll
    for (int off = 1; off < 64; off <<= 1) {
        s += __shfl_xor(s, off);
        s2 += __shfl_xor(s2, off);
    }
    float mu = s * (1.f / 128.f);
    float var = s2 * (1.f / 128.f) - mu * mu;
    float rstd = rsqrtf(fmaxf(var, 0.f) + 1e-5f);
    float g0 = (a0 - mu) * rstd * lng[c0] + lnb[c0];
    float g1 = (a1 - mu) * rstd * lng[c1] + lnb[c1];
    g0 = 0.5f * g0 * (1.f + erff(g0 * 0.70710678118654752f));
    g1 = 0.5f * g1 * (1.f + erff(g1 * 0.70710678118654752f));
    float p0 = g0 * pww[c0] + g1 * pww[c1];
    float p1 = g0 * pww[128 + c0] + g1 * pww[128 + c1];
#pragma unroll
    for (int off = 1; off < 64; off <<= 1) {
        p0 += __shfl_xor(p0, off);
        p1 += __shfl_xor(p1, off);
    }
    // pos on all lanes (identical arithmetic to the old lane-0 path)
    float offy = tanhf(p0) * (2.f / 15.f);
    float offx = tanhf(p1) * (2.f / 15.f);
    float ry = ((float)i + 0.5f) * (2.f / 15.f) - 1.f;
    float rx = ((float)j + 0.5f) * (2.f / 15.f) - 1.f;
    float py = sat(offy + ry, 1.2f), px = sat(offx + rx, 1.2f);
    if (lane == 0) {
        size_t ol = ((size_t)(bl * 4 + g) * 256 + sp) * 2;   // chunk-local
        pos[ol] = py; pos[ol + 1] = px;
        size_t og = ((size_t)(bg * 4 + g) * 256 + sp) * 2;   // global out offset
        out[8388608 + og] = py;  out[8388608 + og + 1] = px;
        out[8421376 + og] = ry;  out[8421376 + og + 1] = rx;
    }
    // fused bilinear sample: channels c0, c1 (same math as old sample_x)
    float gx = (px + 1.f) * 15.5f;
    float gy = (py + 1.f) * 15.5f;
    float x0f = floorf(gx), y0f = floorf(gy);
    int ix0 = (int)x0f, iy0 = (int)y0f;
    float wx1 = gx - x0f, wx0 = 1.f - wx1, wy1 = gy - y0f, wy0 = 1.f - wy1;
    const ushort* xb = xbT + (size_t)bl * 1024 * 512 + g * 128;
    float s0 = 0.f, s1 = 0.f;
#define CORNER(ix, iy, wgt)                                                  \
    if ((unsigned)(ix) < 32u && (unsigned)(iy) < 32u) {                      \
        size_t o = (size_t)((iy) * 32 + (ix)) * 512;                         \
        s0 += (wgt) * bf2f(xb[o + c0]);                                      \
        s1 += (wgt) * bf2f(xb[o + c1]);                                      \
    }
    CORNER(ix0, iy0, wx0 * wy0)
    CORNER(ix0 + 1, iy0, wx1 * wy0)
    CORNER(ix0, iy0 + 1, wx0 * wy1)
    CORNER(ix0 + 1, iy0 + 1, wx1 * wy1)
#undef CORNER
    size_t xo = ((size_t)bl * 256 + sp) * 512 + g * 128;
    xsT[xo + c0] = f2bf(sat(s0, 64.f));
    xsT[xo + c1] = f2bf(sat(s1, 64.f));
}

// ---------------------------------------------------------------------------
// Fused attention v15 = v13 (measured best, 57.9 µs) + s_setprio around MFMA.
//  - R10 post-mortem: two-half s-split made the spill WORSE (47 MB WRITE) and
//    added barrier cost -> reverted to the v13 body verbatim. The ~13-reg
//    spill at (256,4) is invariant to scheduling (R4-R10); 4-blocks-with-spill
//    remains the measured optimum of this structure.
//  - setprio(1) around the QK and PV MFMA clusters (T5): the 4 resident
//    blocks/CU are unsynchronized, so waves sit at diverse phases; boosting
//    MFMA-wave priority keeps the matrix pipe fed (attn +4-7%, m191).
__global__ __launch_bounds__(256, 4) void fused_attn(const ushort* __restrict__ qT,
                                                     const ushort* __restrict__ kT,
                                                     const ushort* __restrict__ vS,
                                                     const uint* __restrict__ tb2,
                                                     const float* __restrict__ pos,
                                                     ushort* __restrict__ outT) {
    __shared__ __align__(16) ushort KP[256 * 64];  // K swz | Ts pairs | P swz
    __shared__ float4 sW4[256];
    __shared__ int sBase[256];
    int bh = blockIdx.y, bl = bh >> 3, h = bh & 7, g = h >> 1;
    int m0 = blockIdx.x * 64;
    int t = threadIdx.x;
    int w = t >> 6, lane = t & 63, col = lane & 15, quad = lane >> 4;
    int mw = w * 16;
    // Q fragment: issue early, latency hides under staging.
    const ushort* qrow = qT + ((size_t)bl * 1024 + m0 + mw + col) * 512 + h * 64;
    short8 a0 = *(const short8*)&qrow[quad * 8];
    short8 a1 = *(const short8*)&qrow[32 + quad * 8];
    {
        const ushort* kb = kT + (size_t)bl * 256 * 512 + h * 64;
        for (int i = t; i < 2048; i += 256) {
            int s = i >> 3, part = i & 7;
            *(uint4*)&KP[s * 64 + ((part ^ (s & 7)) * 8)] =
                *(const uint4*)&kb[(size_t)s * 512 + part * 8];
        }
    }
    {
        int s = t;
        float psy = pos[(size_t)(bl * 4 + g) * 512 + 2 * s];
        float psx = pos[(size_t)(bl * 4 + g) * 512 + 2 * s + 1];
        float syf = 15.5f - 15.5f * psy;
        float sxf = 15.5f - 15.5f * psx;
        float fy = floorf(syf), fx = floorf(sxf);
        float wy1 = syf - fy, wy0 = 1.f - wy1;
        float wx1 = sxf - fx, wx0 = 1.f - wx1;
        sBase[s] = ((int)fy + 4) * 72 + (int)fx + 4;   // slice-local (row rel. m0>>5)
        sW4[s] = make_float4(wx0 * wy0, wx1 * wy0, wx0 * wy1, wx1 * wy1);
    }
    __syncthreads();
    f32x4 acc[16] = {};
    // QK phase 1: ni=0..5 -> K rows 0..95
    __builtin_amdgcn_s_setprio(1);
#pragma unroll
    for (int ni = 0; ni < 6; ni++) {
        int s = ni * 16 + col;
        int x = s & 7;
        short8 b0v = *(const short8*)&KP[s * 64 + ((quad ^ x) * 8)];
        short8 b1v = *(const short8*)&KP[s * 64 + (((quad + 4) ^ x) * 8)];
        acc[ni] = mfma_bf16(a0, b0v, acc[ni]);
        acc[ni] = mfma_bf16(a1, b1v, acc[ni]);
    }
    __builtin_amdgcn_s_setprio(0);
    __syncthreads();   // K rows 0..95 dead (Ts needs bytes [0, 11808))
    // Issue table loads; latency overlaps QK phase 2 + TLP.
    const uint4* tsrc = (const uint4*)(tb2 + (size_t)h * 5184 + (m0 >> 5) * 72);
    uint4 ts0 = tsrc[t];
    uint4 ts1 = tsrc[t + 256];
    uint4 ts2 = (t + 512 < 738) ? tsrc[t + 512] : make_uint4(0, 0, 0, 0);
    // QK phase 2: ni=6..15 -> K rows 96..255 (disjoint from Ts region)
    __builtin_amdgcn_s_setprio(1);
#pragma unroll
    for (int ni = 6; ni < 16; ni++) {
        int s = ni * 16 + col;
        int x = s & 7;
        short8 b0v = *(const short8*)&KP[s * 64 + ((quad ^ x) * 8)];
        short8 b1v = *(const short8*)&KP[s * 64 + (((quad + 4) ^ x) * 8)];
        acc[ni] = mfma_bf16(a0, b0v, acc[ni]);
        acc[ni] = mfma_bf16(a1, b1v, acc[ni]);
    }
    __builtin_amdgcn_s_setprio(0);
    {
        uint4* Tsl4 = (uint4*)KP;
        Tsl4[t] = ts0;
        Tsl4[t + 256] = ts1;
        if (t + 512 < 738) Tsl4[t + 512] = ts2;
    }
    __syncthreads();
    const uint* Tsl = (const uint*)KP;
    // epilogue: logits = acc*scale + rpe bias via LDS pair taps (ds_read_b32)
    int cw = (mw >> 5) * 72 + (mw & 31) + quad * 4;  // slice-local wave/thread const
#pragma unroll
    for (int ni = 0; ni < 16; ni++) {
        int s = ni * 16 + col;
        int base = sBase[s] + cw;
        float4 w4 = sW4[s];
        uint p00 = Tsl[base], p01 = Tsl[base + 2], p02 = Tsl[base + 4];
        uint p10 = Tsl[base + 72], p11 = Tsl[base + 74], p12 = Tsl[base + 76];
        float t0[5], t1[5];
        t0[0] = bflou(p00); t0[1] = bfhiu(p00); t0[2] = bflou(p01);
        t0[3] = bfhiu(p01); t0[4] = bflou(p02);
        t1[0] = bflou(p10); t1[1] = bfhiu(p10); t1[2] = bflou(p11);
        t1[3] = bfhiu(p11); t1[4] = bflou(p12);
#pragma unroll
        for (int r = 0; r < 4; r++) {
            float bias = w4.x * t0[r] + w4.y * t0[r + 1] + w4.z * t1[r] + w4.w * t1[r + 1];
            acc[ni][r] = sat(acc[ni][r] * 0.125f + bias, 64.f);
        }
    }
    // no-max softmax: logits clamped to +-64 -> exp() is safe directly.
    float rinv_[4];
#pragma unroll
    for (int r = 0; r < 4; r++) {
        float sr = 0.f;
#pragma unroll
        for (int ni = 0; ni < 16; ni++) {
            float e = __expf(acc[ni][r]);
            acc[ni][r] = e;
            sr += e;
        }
#pragma unroll
        for (int off = 1; off < 16; off <<= 1) sr += __shfl_xor(sr, off);
        rinv_[r] = 1.f / sr;
    }
    __syncthreads();   // all waves done reading Ts before P overwrites it
#pragma unroll
    for (int ni = 0; ni < 16; ni++)
#pragma unroll
        for (int r = 0; r < 4; r++) {
            int lr = mw + quad * 4 + r;
            int s = ni * 16 + col;
            KP[lr * 256 + (((s >> 3) ^ (lr & 7)) * 8) + (s & 7)] = f2bf(acc[ni][r]);
        }
    // no barrier: PV reads only this wave's P rows; lgkmcnt orders within wave
    f32x4 acc2[4] = {};
    const ushort* vp = vS + ((size_t)bl * 512 + h * 64) * 256;
    int lrA = mw + col, xA = lrA & 7;
    __builtin_amdgcn_s_setprio(1);
#pragma unroll
    for (int ks = 0; ks < 8; ks++) {
        short8 a = *(const short8*)&KP[lrA * 256 + (((ks * 4 + quad) ^ xA) * 8)];
#pragma unroll
        for (int ni = 0; ni < 4; ni++) {
            short8 bb = *(const short8*)&vp[(size_t)(ni * 16 + col) * 256 + ks * 32 + quad * 8];
            acc2[ni] = mfma_bf16(a, bb, acc2[ni]);
        }
    }
    __builtin_amdgcn_s_setprio(0);
#pragma unroll
    for (int ni = 0; ni < 4; ni++)
#pragma unroll
        for (int r = 0; r < 4; r++) {
            int ml = mw + quad * 4 + r;
            float val = sat(acc2[ni][r] * rinv_[r], 64.f);
            outT[((size_t)bl * 1024 + m0 + ml) * 512 + h * 64 + ni * 16 + col] = f2bf(val);
        }
}

// ---------------------------------------------------------------------------
extern "C" void kernel_launch(void* const* d_in, const int* in_sizes, int n_in,
                              void* d_out, int out_size, void* d_ws, size_t ws_size,
                              hipStream_t stream) {
    const float* x   = (const float*)d_in[0];
    const float* Wq  = (const float*)d_in[1];
    const float* bq  = (const float*)d_in[2];
    const float* Wk  = (const float*)d_in[3];
    const float* bk  = (const float*)d_in[4];
    const float* Wv  = (const float*)d_in[5];
    const float* bv  = (const float*)d_in[6];
    const float* Wo  = (const float*)d_in[7];
    const float* bo  = (const float*)d_in[8];
    const float* dww = (const float*)d_in[9];
    const float* dwb = (const float*)d_in[10];
    const float* lng = (const float*)d_in[11];
    const float* lnb = (const float*)d_in[12];
    const float* pww = (const float*)d_in[13];
    const float* rpe = (const float*)d_in[14];
    float* out = (float*)d_out;

    char* wsb = (char*)d_ws;
    size_t off = 256;
    const size_t Wbf_bytes = (size_t)4 * 262144 * 2;  // 2 MB
    const size_t tb2_bytes = (size_t)8 * 5184 * 4;    // ~162 KB (pair-packed)
    ushort* Wbf = (ushort*)(wsb + off); off += Wbf_bytes;
    uint*   tb2 = (uint*)(wsb + off);   off += tb2_bytes;
    size_t base = (off + 255) & ~(size_t)255;

    const size_t xbT_b = (size_t)1024 * 512 * 2;   // 1 MB
    const size_t qT_b  = (size_t)1024 * 512 * 2;   // 1 MB
    const size_t xsT_b = (size_t)256 * 512 * 2;    // 256 KB
    const size_t kT_b  = (size_t)256 * 512 * 2;    // 256 KB
    const size_t vS_b  = (size_t)512 * 256 * 2;    // 256 KB
    const size_t oT_b  = (size_t)1024 * 512 * 2;   // 1 MB
    const size_t pos_b = (size_t)4 * 256 * 2 * 4;  // 8 KB
    const size_t per_b = xbT_b + qT_b + xsT_b + kT_b + vS_b + oT_b + pos_b + 1024;
    long long avail = (long long)ws_size - (long long)base;
    int bc_cap = (int)(avail > 0 ? avail / (long long)per_b : 0);
    if (bc_cap < 1) bc_cap = 1;
    if (bc_cap > 16) bc_cap = 16;

    prep_w<<<dim3(256, 4), 256, 0, stream>>>(Wq, Wk, Wv, Wo, Wbf);
    prep_rpe<<<8, 256, 0, stream>>>(rpe, tb2);
    const ushort* Wqb = Wbf;
    const ushort* Wkb = Wbf + 262144;
    const ushort* Wob = Wbf + 3 * 262144;

    for (int b0 = 0; b0 < 16; b0 += bc_cap) {
        int bc = 16 - b0 < bc_cap ? 16 - b0 : bc_cap;
        char* p = wsb + base;
        ushort* xbT  = (ushort*)p; p += xbT_b * bc;
        ushort* qT   = (ushort*)p; p += qT_b * bc;
        ushort* xsT  = (ushort*)p; p += xsT_b * bc;
        ushort* kT   = (ushort*)p; p += kT_b * bc;
        ushort* vS   = (ushort*)p; p += vS_b * bc;
        ushort* outT = (ushort*)p; p += oT_b * bc;
        float*  pos  = (float*)p;

        prep_xT<<<dim3(32, 8, bc), 256, 0, stream>>>(x, xbT, b0);
        gemm128<1, 1><<<dim3(8, 4, bc), 256, 0, stream>>>(Wqb, xbT, bq, qT, 512,
                                                          (size_t)1024 * 512, (size_t)1024 * 512, 512, 0);
        offset_net<<<dim3(256, 4 * bc), 64, 0, stream>>>(qT, dww, dwb, lng, lnb, pww,
                                                         xbT, pos, xsT, out, b0);
        gemm_kv<<<dim3(4, 16, bc), 256, 0, stream>>>(Wkb, xsT, bk, bv, kT, vS);
        fused_attn<<<dim3(16, 8 * bc), 256, 0, stream>>>(qT, kT, vS, tb2, pos, outT);
        gemm128<0, 0><<<dim3(8, 4, bc), 256, 0, stream>>>(Wob, outT, bo, d_out, 512,
                                                          (size_t)1024 * 512, (size_t)512 * 1024, 1024,
                                                          (size_t)b0 * 512 * 1024);
    }
}